// Round 2
// 1954.475 us; speedup vs baseline: 1.0596x; 1.0596x over previous
//
#include <hip/hip_runtime.h>
#include <cstdint>
#include <cstddef>
#include <type_traits>

#define N_ATOMS 500000
#define NFEAT 9
#define DIM 300
#define NSEG4 75      // DIM/4 float4 per row
#define NT 512

// ---- fast-path main kernel geometry ----
#define BM2 64        // atoms per block (== 1 wave)
#define BN2 32        // tokens per chunk
#define BK2 20        // K-chunk (divides 300)
#define BKSEG2 5      // BK2/4 float4 per row per chunk
#define REFINE_THR 0.0625f   // fp64-refine only near-ties (>=50x fp32 score error)

// ---- ws layout ----
// 0       : double loss_part[256]   (2048)
// 2048    : double wnormd[512]      (4096)
// 6144    : float  wnormf[512]      (2048)
// 8192    : int    counters[8]      (32)   [0..3]=counts, [4..7]=cursors
// 8256    : int    order[N_ATOMS]   (2,000,000)
#define WS_FAST_NEED 2008256

__device__ __forceinline__ void classRange(int v, int& lo, int& hi) {
  if (v == 5)      { lo = 0;   hi = 377; }
  else if (v == 6) { lo = 378; hi = 433; }
  else if (v == 7) { lo = 434; hi = 488; }
  else             { lo = 489; hi = 511; }
}
__device__ __forceinline__ int classOf(int v) {
  return (v == 5) ? 0 : (v == 6) ? 1 : (v == 7) ? 2 : 3;
}

// K0: token norms (fp64 + fp32), zero loss partials + counters.
__global__ __launch_bounds__(256) void k_prep(const float* __restrict__ w,
    double* __restrict__ wnormd, float* __restrict__ wnormf,
    double* __restrict__ loss_part, int* __restrict__ counters)
{
  const int t = blockIdx.x * 4 + (threadIdx.x >> 6);
  const int lane = threadIdx.x & 63;
  double s = 0.0;
  for (int j = lane; j < DIM; j += 64) {
    const double v = (double)w[(size_t)t * DIM + j];
    s = fma(v, v, s);
  }
  #pragma unroll
  for (int off = 32; off; off >>= 1) s += __shfl_down(s, off);
  if (lane == 0) { wnormd[t] = s; wnormf[t] = (float)s; }
  if (blockIdx.x == 0) {
    loss_part[threadIdx.x] = 0.0;
    if (threadIdx.x < 8) counters[threadIdx.x] = 0;
  }
}

// K1: class histogram (block-aggregated)
__global__ __launch_bounds__(256) void k_count(const int* __restrict__ x,
                                               int* __restrict__ counters)
{
  __shared__ int c[4];
  if (threadIdx.x < 4) c[threadIdx.x] = 0;
  __syncthreads();
  const int a = blockIdx.x * 256 + threadIdx.x;
  if (a < N_ATOMS) atomicAdd(&c[classOf(x[(size_t)a * NFEAT])], 1);
  __syncthreads();
  if (threadIdx.x < 4) atomicAdd(&counters[threadIdx.x], c[threadIdx.x]);
}

// K2: exclusive scan of 4 counts -> cursors
__global__ void k_scan(int* __restrict__ counters)
{
  if (threadIdx.x == 0) {
    const int c0 = counters[0], c1 = counters[1], c2 = counters[2];
    counters[4] = 0;
    counters[5] = c0;
    counters[6] = c0 + c1;
    counters[7] = c0 + c1 + c2;
  }
}

// K3: scatter atom ids into class-sorted order[] (block-aggregated atomics)
__global__ __launch_bounds__(256) void k_scatter(const int* __restrict__ x,
    int* __restrict__ counters, int* __restrict__ order)
{
  __shared__ int cnt[4], base[4];
  if (threadIdx.x < 4) cnt[threadIdx.x] = 0;
  __syncthreads();
  const int a = blockIdx.x * 256 + threadIdx.x;
  int cl = 0, rank = 0;
  if (a < N_ATOMS) {
    cl = classOf(x[(size_t)a * NFEAT]);
    rank = atomicAdd(&cnt[cl], 1);
  }
  __syncthreads();
  if (threadIdx.x < 4) base[threadIdx.x] = atomicAdd(&counters[4 + threadIdx.x], cnt[threadIdx.x]);
  __syncthreads();
  if (a < N_ATOMS) order[base[cl] + rank] = a;
}

// K4 v2b: single-wave blocks, 64 atoms x 32-token chunks, BK=20 staging with
// DOUBLE-BUFFERED LDS (no aliasing between compute reads and prefetch writes,
// no barriers), 8x4 register tile, runtime-jmax to skip padded token columns,
// near-tie-only fp64 refinement, fused output gather, fused loss.
__global__ __launch_bounds__(64) void k_main2(
    const int* __restrict__ x, const float* __restrict__ e,
    const float* __restrict__ w, const int* __restrict__ order,
    const float* __restrict__ wnormf, const double* __restrict__ wnormd,
    float* __restrict__ out, double* __restrict__ loss_part)
{
  __shared__ float4 eT[2][BM2 * BKSEG2];   // 2 x 5.1 KB
  __shared__ float4 wT[2][BN2 * BKSEG2];   // 2 x 2.6 KB
  __shared__ int s_aid[BM2], s_lo[BM2], s_hi[BM2], s_kb[BM2], s_k2[BM2];

  const int lane = threadIdx.x;                 // block == 1 wave of 64
  const int g = blockIdx.x * BM2 + lane;
  const int a0 = (g < N_ATOMS) ? order[g] : -1;
  s_aid[lane] = a0;
  int lo = 1 << 30, hi = 0;
  if (a0 >= 0) classRange(x[(size_t)a0 * NFEAT], lo, hi);
  s_lo[lane] = lo; s_hi[lane] = hi;
  int kmn = lo, kmx = hi;
  #pragma unroll
  for (int off = 32; off; off >>= 1) {
    kmn = min(kmn, __shfl_xor(kmn, off));
    kmx = max(kmx, __shfl_xor(kmx, off));
  }

  // per-lane staging coords (constant per block): flat f4 index s -> (row, col)
  const float* eptr[5];
  #pragma unroll
  for (int p = 0; p < 5; ++p) {
    const int s = lane + 64 * p;                // 0..319 over e-tile
    const int r = s / BKSEG2, c = s - r * BKSEG2;
    const int ar = s_aid[r];
    eptr[p] = (ar >= 0) ? (e + (size_t)ar * DIM + 4 * c) : (const float*)nullptr;
  }
  int wrow[3], wcol[3];
  #pragma unroll
  for (int p = 0; p < 3; ++p) {
    const int s = lane + 64 * p;                // 0..159 valid over w-tile
    const int r = s / BKSEG2, c = s - r * BKSEG2;
    wrow[p] = r; wcol[p] = 4 * c;
  }
  const int tx = lane & 7;                      // atom group: atoms tx+8i
  const int ty = lane >> 3;                     // token group: tokens ty+8j

  float m1[8], m2[8]; int q1[8], q2[8];
  #pragma unroll
  for (int i = 0; i < 8; ++i) {
    m1[i] = __builtin_inff(); m2[i] = __builtin_inff();
    q1[i] = 0x7fffffff; q2[i] = 0x7fffffff;
  }
  float en_part = 0.f;

  auto run_chunk = [&](auto JC, const int k0, const int kn, const bool firstTok) {
    constexpr int J = decltype(JC)::value;
    float acc[8][J];
    #pragma unroll
    for (int i = 0; i < 8; ++i)
      #pragma unroll
      for (int j = 0; j < J; ++j) acc[i][j] = 0.f;

    const float* wptr[3];
    #pragma unroll
    for (int p = 0; p < 3; ++p) {
      const int rr = min(k0 + wrow[p], NT - 1);  // clamp: rows >= kn guarded at use
      wptr[p] = w + (size_t)rr * DIM + wcol[p];
    }

    float4 eR[5], wR[3];
    // prologue: chunk kc=0 -> regs -> LDS buf 0
    #pragma unroll
    for (int p = 0; p < 5; ++p) {
      float4 v = make_float4(0.f, 0.f, 0.f, 0.f);
      if (eptr[p]) v = *(const float4*)(eptr[p]);
      eR[p] = v;
    }
    #pragma unroll
    for (int p = 0; p < 3; ++p)
      if (lane + 64 * p < BN2 * BKSEG2) wR[p] = *(const float4*)(wptr[p]);
    if (firstTok) {
      #pragma unroll
      for (int p = 0; p < 5; ++p) {
        en_part = fmaf(eR[p].x, eR[p].x, en_part);
        en_part = fmaf(eR[p].y, eR[p].y, en_part);
        en_part = fmaf(eR[p].z, eR[p].z, en_part);
        en_part = fmaf(eR[p].w, eR[p].w, en_part);
      }
    }
    #pragma unroll
    for (int p = 0; p < 5; ++p) eT[0][lane + 64 * p] = eR[p];
    #pragma unroll
    for (int p = 0; p < 3; ++p)
      if (lane + 64 * p < BN2 * BKSEG2) wT[0][lane + 64 * p] = wR[p];

    int buf = 0;
    for (int kc = BK2; kc <= DIM; kc += BK2) {
      const bool more = (kc < DIM);
      if (more) {   // issue next chunk's loads BEFORE compute (latency hides)
        #pragma unroll
        for (int p = 0; p < 5; ++p) {
          float4 v = make_float4(0.f, 0.f, 0.f, 0.f);
          if (eptr[p]) v = *(const float4*)(eptr[p] + kc);
          eR[p] = v;
        }
        #pragma unroll
        for (int p = 0; p < 3; ++p)
          if (lane + 64 * p < BN2 * BKSEG2) wR[p] = *(const float4*)(wptr[p] + kc);
        if (firstTok) {
          #pragma unroll
          for (int p = 0; p < 5; ++p) {
            en_part = fmaf(eR[p].x, eR[p].x, en_part);
            en_part = fmaf(eR[p].y, eR[p].y, en_part);
            en_part = fmaf(eR[p].z, eR[p].z, en_part);
            en_part = fmaf(eR[p].w, eR[p].w, en_part);
          }
        }
      }
      // compute currently-staged chunk (LDS reads are 8-way broadcast)
      #pragma unroll
      for (int c4 = 0; c4 < BKSEG2; ++c4) {
        float4 av[8];
        #pragma unroll
        for (int i = 0; i < 8; ++i) av[i] = eT[buf][(tx + 8 * i) * BKSEG2 + c4];
        #pragma unroll
        for (int j = 0; j < J; ++j) {
          const float4 bv = wT[buf][(ty + 8 * j) * BKSEG2 + c4];
          #pragma unroll
          for (int i = 0; i < 8; ++i) {
            acc[i][j] = fmaf(av[i].x, bv.x, acc[i][j]);
            acc[i][j] = fmaf(av[i].y, bv.y, acc[i][j]);
            acc[i][j] = fmaf(av[i].z, bv.z, acc[i][j]);
            acc[i][j] = fmaf(av[i].w, bv.w, acc[i][j]);
          }
        }
      }
      if (more) {   // write next chunk into the OTHER buffer (no aliasing)
        #pragma unroll
        for (int p = 0; p < 5; ++p) eT[buf ^ 1][lane + 64 * p] = eR[p];
        #pragma unroll
        for (int p = 0; p < 3; ++p)
          if (lane + 64 * p < BN2 * BKSEG2) wT[buf ^ 1][lane + 64 * p] = wR[p];
        buf ^= 1;
      }
    }

    // top-2 update (same summation order + tie rules as verified kernel)
    int rlo[8], rhi[8];
    #pragma unroll
    for (int i = 0; i < 8; ++i) { rlo[i] = s_lo[tx + 8 * i]; rhi[i] = s_hi[tx + 8 * i]; }
    #pragma unroll
    for (int j = 0; j < J; ++j) {
      const int tloc = ty + 8 * j;
      const int k = k0 + tloc;
      const bool kv = (tloc < kn);
      float wn = 0.f;
      if (kv) wn = wnormf[k];
      #pragma unroll
      for (int i = 0; i < 8; ++i) {
        const float sc = fmaf(-2.f, acc[i][j], wn);  // == wn - 2*acc, 1 rounding
        const bool ok = kv && (k >= rlo[i]) && (k < rhi[i]);
        if (ok) {
          if (sc < m1[i]) { m2[i] = m1[i]; q2[i] = q1[i]; m1[i] = sc; q1[i] = k; }
          else if (sc < m2[i]) { m2[i] = sc; q2[i] = k; }
        }
      }
    }
  };

  bool first = true;
  for (int k0 = kmn; k0 < kmx; k0 += BN2) {
    const int kn = min(BN2, kmx - k0);
    const int jm = (kn + 7) >> 3;
    if      (jm == 4) run_chunk(std::integral_constant<int,4>{}, k0, kn, first);
    else if (jm == 3) run_chunk(std::integral_constant<int,3>{}, k0, kn, first);
    else if (jm == 2) run_chunk(std::integral_constant<int,2>{}, k0, kn, first);
    else              run_chunk(std::integral_constant<int,1>{}, k0, kn, first);
    first = false;
  }

  // merge top-2 across the 8 token-threads sharing each atom set (in-wave)
  #pragma unroll
  for (int off = 8; off <= 32; off <<= 1) {
    #pragma unroll
    for (int i = 0; i < 8; ++i) {
      float n1 = __shfl_xor(m1[i], off), n2 = __shfl_xor(m2[i], off);
      int j1 = __shfl_xor(q1[i], off), j2 = __shfl_xor(q2[i], off);
      if (n1 < m1[i] || (n1 == m1[i] && j1 < q1[i])) {
        const float tf = m1[i]; const int tk = q1[i];
        m1[i] = n1; q1[i] = j1; n1 = tf; j1 = tk;
      }
      if (n1 < m2[i] || (n1 == m2[i] && j1 < q2[i])) { m2[i] = n1; q2[i] = j1; }
      if (n2 < m2[i] || (n2 == m2[i] && j2 < q2[i])) { m2[i] = n2; q2[i] = j2; }
    }
  }

  // clear winners: pick k1, loss uses fp32 score; near-ties flagged for fp64
  double wloss = 0.0;
  unsigned long long refmask = 0ull;
  #pragma unroll
  for (int i = 0; i < 8; ++i) {
    const int ai = tx + 8 * i;
    const bool mine = (ty == 0) && (s_aid[ai] >= 0);
    const bool need = mine && (m2[i] - m1[i] < REFINE_THR);
    if (mine) {
      s_kb[ai] = q1[i];
      s_k2[ai] = q2[i];
      if (!need) wloss += (double)m1[i];
    }
    const unsigned long long b = __ballot(need);   // bit tx -> atom tx+8i
    refmask |= (b & 0xffull) << (8 * i);
  }

  // fp64 refinement of flagged atoms only (wave-cooperative, <=64 iterations)
  while (refmask) {
    const int ai = __builtin_ctzll(refmask);
    refmask &= refmask - 1ull;
    const int ag = s_aid[ai];
    const int kk1 = s_kb[ai], kk2 = s_k2[ai];
    const float* erow = e + (size_t)ag * DIM;
    const float* w1 = w + (size_t)kk1 * DIM;
    const float* w2 = w + (size_t)kk2 * DIM;
    double d1 = 0.0, d2 = 0.0;
    for (int d = lane; d < DIM; d += 64) {
      const double ev = (double)erow[d];
      d1 = fma(ev, (double)w1[d], d1);
      d2 = fma(ev, (double)w2[d], d2);
    }
    #pragma unroll
    for (int off = 32; off; off >>= 1) {
      d1 += __shfl_xor(d1, off);
      d2 += __shfl_xor(d2, off);
    }
    const double s1d = wnormd[kk1] - 2.0 * d1;
    const double s2d = wnormd[kk2] - 2.0 * d2;
    int kb; double db;
    if (s2d < s1d || (s2d == s1d && kk2 < kk1)) { kb = kk2; db = s2d; }
    else { kb = kk1; db = s1d; }
    if (lane == 0) { s_kb[ai] = kb; wloss += db; }
  }

  // fused gather: write output rows (w rows are L1/L2-hot)
  for (int s = lane; s < BM2 * NSEG4; s += 64) {
    const int ai = s / NSEG4;
    const int c = s - ai * NSEG4;
    const int ag = s_aid[ai];
    if (ag >= 0) {
      const int kb = s_kb[ai];
      *(float4*)(out + (size_t)ag * DIM + 4 * c) =
          *(const float4*)(w + (size_t)kb * DIM + 4 * c);
    }
  }

  // loss partial: sum(en + d_best) over block
  double tot = wloss + (double)en_part;
  #pragma unroll
  for (int off = 32; off; off >>= 1) tot += __shfl_xor(tot, off);
  if (lane == 0) atomicAdd(&loss_part[blockIdx.x & 255], tot);
}

// K6: reduce loss partials, write scalar
__global__ void k_final(const double* __restrict__ loss_part, float* __restrict__ out)
{
  __shared__ double sm[256];
  const int tid = threadIdx.x;
  sm[tid] = loss_part[tid];
  __syncthreads();
  for (int s = 128; s; s >>= 1) {
    if (tid < s) sm[tid] += sm[tid + s];
    __syncthreads();
  }
  if (tid == 0)
    out[(size_t)N_ATOMS * DIM] = (float)(1.25 * sm[0] / ((double)N_ATOMS * (double)DIM));
}

// Fallback (tiny ws): fused wave-per-atom, slow but correct.
__global__ __launch_bounds__(256) void k_fallback(
    const int* __restrict__ x, const float* __restrict__ e, const float* __restrict__ w,
    const float* __restrict__ wnormf, const double* __restrict__ wnormd,
    double* __restrict__ loss_part, float* __restrict__ out)
{
  const int wv = threadIdx.x >> 6, lane = threadIdx.x & 63;
  const int a = blockIdx.x * 4 + wv;
  if (a >= N_ATOMS) return;
  int lo, hi; classRange(x[(size_t)a * NFEAT], lo, hi);
  float er[5];
  #pragma unroll
  for (int j = 0; j < 5; j++) {
    const int d = j * 64 + lane;
    er[j] = (d < DIM) ? e[(size_t)a * DIM + d] : 0.f;
  }
  float m1 = __builtin_inff(), m2 = __builtin_inff();
  int k1 = 0x7fffffff, k2 = 0x7fffffff;
  const int iters = (hi - lo + 63) >> 6;
  for (int it = 0; it < iters; it++) {
    const int k = lo + it * 64 + lane;
    const bool val = (k < hi);
    const int ks = val ? k : lo;
    const float* wr = w + (size_t)ks * DIM;
    float acc = 0.f;
    #pragma unroll
    for (int j = 0; j < 5; j++) {
      const int dmax = min(64, DIM - j * 64);
      for (int dd = 0; dd < dmax; dd++)
        acc = fmaf(__shfl(er[j], dd), wr[j * 64 + dd], acc);
    }
    if (val) {
      const float sc = wnormf[k] - 2.0f * acc;
      if (sc < m1) { m2 = m1; k2 = k1; m1 = sc; k1 = k; }
      else if (sc < m2) { m2 = sc; k2 = k; }
    }
  }
  #pragma unroll
  for (int off = 32; off; off >>= 1) {
    float n1 = __shfl_xor(m1, off), n2 = __shfl_xor(m2, off);
    int j1 = __shfl_xor(k1, off), j2 = __shfl_xor(k2, off);
    if (n1 < m1 || (n1 == m1 && j1 < k1)) {
      const float tf = m1; const int tk = k1;
      m1 = n1; k1 = j1; n1 = tf; j1 = tk;
    }
    if (n1 < m2 || (n1 == m2 && j1 < k2)) { m2 = n1; k2 = j1; }
    if (n2 < m2 || (n2 == m2 && j2 < k2)) { m2 = n2; k2 = j2; }
  }
  double d1 = 0.0, d2 = 0.0, en = 0.0;
  const float* w1 = w + (size_t)k1 * DIM;
  const float* w2 = w + (size_t)k2 * DIM;
  for (int d = lane; d < DIM; d += 64) {
    const double ev = (double)e[(size_t)a * DIM + d];
    en = fma(ev, ev, en);
    d1 = fma(ev, (double)w1[d], d1);
    d2 = fma(ev, (double)w2[d], d2);
  }
  #pragma unroll
  for (int off = 32; off; off >>= 1) {
    en += __shfl_xor(en, off);
    d1 += __shfl_xor(d1, off);
    d2 += __shfl_xor(d2, off);
  }
  const double s1 = wnormd[k1] - 2.0 * d1;
  const double s2 = wnormd[k2] - 2.0 * d2;
  int kb; double db;
  if (s2 < s1 || (s2 == s1 && k2 < k1)) { kb = k2; db = s2; }
  else { kb = k1; db = s1; }
  #pragma unroll
  for (int j = 0; j < 5; j++) {
    const int d = j * 64 + lane;
    if (d < DIM) out[(size_t)a * DIM + d] = w[(size_t)kb * DIM + d];
  }
  if (lane == 0) atomicAdd(&loss_part[a & 255], en + db);
}

extern "C" void kernel_launch(void* const* d_in, const int* in_sizes, int n_in,
                              void* d_out, int out_size, void* d_ws, size_t ws_size,
                              hipStream_t stream)
{
  const int*   x = (const int*)d_in[0];
  const float* e = (const float*)d_in[1];
  const float* w = (const float*)d_in[2];
  float* out = (float*)d_out;
  char* ws = (char*)d_ws;

  double* loss_part = (double*)ws;                 // 256 doubles
  double* wnormd    = (double*)(ws + 2048);        // 512 doubles
  float*  wnormf    = (float*)(ws + 6144);         // 512 floats
  int*    counters  = (int*)(ws + 8192);           // 8 ints
  int*    order     = (int*)(ws + 8256);           // 500000 ints

  k_prep<<<dim3(128), dim3(256), 0, stream>>>(w, wnormd, wnormf, loss_part, counters);

  if (ws_size >= (size_t)WS_FAST_NEED) {
    const int nb = (N_ATOMS + 255) / 256;          // 1954
    k_count<<<dim3(nb), dim3(256), 0, stream>>>(x, counters);
    k_scan<<<dim3(1), dim3(64), 0, stream>>>(counters);
    k_scatter<<<dim3(nb), dim3(256), 0, stream>>>(x, counters, order);
    k_main2<<<dim3((N_ATOMS + BM2 - 1) / BM2), dim3(64), 0, stream>>>(
        x, e, w, order, wnormf, wnormd, out, loss_part);
  } else {
    k_fallback<<<dim3((N_ATOMS + 3) / 4), dim3(256), 0, stream>>>(
        x, e, w, wnormf, wnormd, loss_part, out);
  }
  k_final<<<dim3(1), dim3(256), 0, stream>>>(loss_part, out);
}